// Round 4
// baseline (140.007 us; speedup 1.0000x reference)
//
#include <hip/hip_runtime.h>

#define N_MENT   10000
#define BATCH    512
#define N_ANTS   50
#define EMB      1024
#define PW_EMB   64
#define IN_F     3136       // 3*EMB + PW_EMB
#define HID      128
#define M_TOT    (BATCH * N_ANTS)   // 25600
#define EPS_VAL  1e-7f
#define SLOPE    0.01f
#define NKT      98         // IN_F / 32 k-tiles

#define AMAB_ROWS  (BATCH + N_MENT)          // 10512
#define AMAB_BLK   165                        // ceil(10512/16/4)
#define MAIN_BLK   (M_TOT / 64)               // 400
#define TOT_BLK    (AMAB_BLK + MAIN_BLK)      // 565

using f32x4 = __attribute__((ext_vector_type(4))) float;
using s16x8 = __attribute__((ext_vector_type(8))) short;
using u16x8 = __attribute__((ext_vector_type(8))) unsigned short;

__device__ __forceinline__ unsigned short f2bf(float f) {
  unsigned u = __builtin_bit_cast(unsigned, f);
  u += 0x7FFFu + ((u >> 16) & 1u);   // RNE
  return (unsigned short)(u >> 16);
}

// pack 8 f32 -> 8 bf16 (RNE) via v_cvt_pk_bf16_f32
__device__ __forceinline__ s16x8 pack8(float4 lo, float4 hi) {
  union { s16x8 v; unsigned u[4]; } r;
  asm("v_cvt_pk_bf16_f32 %0, %1, %2" : "=v"(r.u[0]) : "v"(lo.x), "v"(lo.y));
  asm("v_cvt_pk_bf16_f32 %0, %1, %2" : "=v"(r.u[1]) : "v"(lo.z), "v"(lo.w));
  asm("v_cvt_pk_bf16_f32 %0, %1, %2" : "=v"(r.u[2]) : "v"(hi.x), "v"(hi.y));
  asm("v_cvt_pk_bf16_f32 %0, %1, %2" : "=v"(r.u[3]) : "v"(hi.z), "v"(hi.w));
  return r.v;
}

// ---- kernel 0: W1 [3136][128] f32 -> w1f in MFMA B-fragment-linear order ----
// w1f element index = ((tn*NKT + tk)*64 + lane)*8 + j
//   lane = ln + lg*16 holds B[col = tn*16+ln][k = tk*32 + lg*8 + j]
__global__ __launch_bounds__(256) void k_convert(const float* __restrict__ w1,
                                                 unsigned short* __restrict__ w1f) {
  const int id   = blockIdx.x * 256 + threadIdx.x;   // 0..50175
  const int lane = id & 63;
  const int tile = id >> 6;                          // 0..783 = 8*98
  const int tk   = tile % NKT, tn = tile / NKT;
  const int n    = tn * 16 + (lane & 15);
  const int k    = tk * 32 + (lane >> 4) * 8;
  u16x8 o;
  #pragma unroll
  for (int j = 0; j < 8; ++j) o[j] = f2bf(w1[(size_t)(k + j) * HID + n]);
  *(u16x8*)(w1f + (size_t)id * 8) = o;
}

// load 8 B-fragments (full HID) for k-tile TK; wl = w1f + lane*8
#define BLOAD(BF, TK)                                                        \
  {                                                                          \
    _Pragma("unroll")                                                        \
    for (int nf = 0; nf < 8; ++nf)                                           \
      BF[nf] = *(const s16x8*)(wl + (size_t)(nf * NKT + (TK)) * 512);        \
  }

// ---- fused kernel: amab-role blocks + main-role blocks, spin-joined --------
__global__ __launch_bounds__(256, 3) void k_fused(
    const float* __restrict__ all_m, const float* __restrict__ men,
    const float* __restrict__ pw, const int* __restrict__ topi,
    const float* __restrict__ rough, const unsigned short* __restrict__ w1f,
    float* __restrict__ amab, const float* __restrict__ b1,
    const float* __restrict__ wout, const float* __restrict__ bout,
    float* __restrict__ out, unsigned* __restrict__ cnt) {
  const int tid  = threadIdx.x;
  const int bid  = blockIdx.x;
  const int lane = tid & 63, wid = tid >> 6;
  const int ln   = lane & 15, lg = lane >> 4;
  const unsigned short* wl = w1f + (size_t)lane * 8;
  const float4 Z = make_float4(0.f, 0.f, 0.f, 0.f);

  if (bid < AMAB_BLK) {
    // ================= role A: AM/AB precompute ==========================
    const int gw   = bid * 4 + wid;          // 0..659 (657 useful)
    const int row0 = gw * 16;
    const int sr   = (row0 + ln < AMAB_ROWS) ? row0 + ln : AMAB_ROWS - 1;
    const bool isAM = (row0 < BATCH);        // wave-uniform (512 % 16 == 0)
    const float* srcp = isAM ? (men + (size_t)sr * EMB)
                             : (all_m + (size_t)(sr - BATCH) * EMB);
    srcp += lg * 8;
    const int tkb = isAM ? 0 : 32;

    f32x4 acc[8] = {};
    float4 a00 = ((const float4*)srcp)[0],      a01 = ((const float4*)srcp)[1];
    float4 a10 = ((const float4*)(srcp + 32))[0], a11 = ((const float4*)(srcp + 32))[1];

    for (int p = 0; p < 16; ++p) {
      const int t0 = 2 * p;
      float4 n00 = Z, n01 = Z, n10 = Z, n11 = Z;
      if (t0 + 2 < 32) {
        n00 = ((const float4*)(srcp + (t0 + 2) * 32))[0];
        n01 = ((const float4*)(srcp + (t0 + 2) * 32))[1];
      }
      {
        s16x8 bf[8]; BLOAD(bf, tkb + t0);
        s16x8 af = pack8(a00, a01);
        #pragma unroll
        for (int nf = 0; nf < 8; ++nf)
          acc[nf] = __builtin_amdgcn_mfma_f32_16x16x32_bf16(af, bf[nf], acc[nf], 0, 0, 0);
      }
      if (t0 + 3 < 32) {
        n10 = ((const float4*)(srcp + (t0 + 3) * 32))[0];
        n11 = ((const float4*)(srcp + (t0 + 3) * 32))[1];
      }
      {
        s16x8 bf[8]; BLOAD(bf, tkb + t0 + 1);
        s16x8 af = pack8(a10, a11);
        #pragma unroll
        for (int nf = 0; nf < 8; ++nf)
          acc[nf] = __builtin_amdgcn_mfma_f32_16x16x32_bf16(af, bf[nf], acc[nf], 0, 0, 0);
      }
      a00 = n00; a01 = n01; a10 = n10; a11 = n11;
    }
    #pragma unroll
    for (int nf = 0; nf < 8; ++nf)
      #pragma unroll
      for (int e = 0; e < 4; ++e) {
        const int r = row0 + lg * 4 + e;
        if (r < AMAB_ROWS) amab[(size_t)r * HID + nf * 16 + ln] = acc[nf][e];
      }
    __threadfence();          // device-scope release of amab writes
    __syncthreads();
    if (tid == 0) atomicAdd(&cnt[0], 1u);
    return;
  }

  // =================== role B: main fused GEMM ===========================
  const int mb   = bid - AMAB_BLK;          // 0..399
  const int m0w  = mb * 64 + wid * 16;
  const int mrow = m0w + ln;
  const int bbr  = mrow / N_ANTS;
  const int bir  = topi[mrow];
  const float* pa = men   + (size_t)bbr  * EMB    + lg * 8;
  const float* pb = all_m + (size_t)bir  * EMB    + lg * 8;
  const float* pp = pw    + (size_t)mrow * PW_EMB + lg * 8;

  f32x4 acc[8] = {};

#define LDT_AB(tt, A0, A1, B0, B1)                                           \
  if ((tt) < 32) {                                                           \
    A0 = ((const float4*)(pa + (tt) * 32))[0];                               \
    A1 = ((const float4*)(pa + (tt) * 32))[1];                               \
    B0 = ((const float4*)(pb + (tt) * 32))[0];                               \
    B1 = ((const float4*)(pb + (tt) * 32))[1];                               \
  } else if ((tt) < 34) {                                                    \
    A0 = ((const float4*)(pp + ((tt) - 32) * 32))[0];                        \
    A1 = ((const float4*)(pp + ((tt) - 32) * 32))[1];                        \
    B0 = make_float4(1.f, 1.f, 1.f, 1.f);  B1 = B0;                          \
  }

#define STEP_MAIN(A0, A1, B0, B1, TK)                                        \
  {                                                                          \
    s16x8 bf[8]; BLOAD(bf, (TK));                                            \
    float4 plo = make_float4(A0.x * B0.x, A0.y * B0.y, A0.z * B0.z, A0.w * B0.w); \
    float4 phi = make_float4(A1.x * B1.x, A1.y * B1.y, A1.z * B1.z, A1.w * B1.w); \
    s16x8 af = pack8(plo, phi);                                              \
    _Pragma("unroll")                                                        \
    for (int nf = 0; nf < 8; ++nf)                                           \
      acc[nf] = __builtin_amdgcn_mfma_f32_16x16x32_bf16(af, bf[nf], acc[nf], 0, 0, 0); \
  }

  float4 a00 = Z, a01 = Z, b00 = Z, b01 = Z, a10 = Z, a11 = Z, b10 = Z, b11 = Z;
  LDT_AB(0, a00, a01, b00, b01);
  LDT_AB(1, a10, a11, b10, b11);

  for (int p = 0; p < 17; ++p) {           // 34 k-tiles: 32 sim + 2 pw
    const int t0 = 2 * p;
    float4 n00 = Z, n01 = Z, m00 = Z, m01 = Z;
    float4 n10 = Z, n11 = Z, m10 = Z, m11 = Z;
    LDT_AB(t0 + 2, n00, n01, m00, m01);
    STEP_MAIN(a00, a01, b00, b01, 64 + t0);
    LDT_AB(t0 + 3, n10, n11, m10, m11);
    STEP_MAIN(a10, a11, b10, b11, 64 + t0 + 1);
    a00 = n00; a01 = n01; b00 = m00; b01 = m01;
    a10 = n10; a11 = n11; b10 = m10; b11 = m11;
  }

  // wait for amab role to finish (all blocks co-resident by launch_bounds)
  if (tid == 0) {
    while (__hip_atomic_load(&cnt[0], __ATOMIC_ACQUIRE, __HIP_MEMORY_SCOPE_AGENT)
           < (unsigned)AMAB_BLK)
      __builtin_amdgcn_s_sleep(2);
  }
  __syncthreads();

  // epilogue: + AM[bb] + AB[idx] + b1, leaky, dot W_out, reduce over n
  float b1v[8], wv[8];
  #pragma unroll
  for (int nf = 0; nf < 8; ++nf) {
    b1v[nf] = b1[nf * 16 + ln];
    wv[nf]  = wout[nf * 16 + ln];
  }
  const float bo = bout[0];
  #pragma unroll
  for (int e = 0; e < 4; ++e) {
    const int rowe = m0w + lg * 4 + e;
    const int bbe  = rowe / N_ANTS;
    const int gie  = topi[rowe];
    const float* amr = amab + (size_t)bbe * HID;
    const float* abr = amab + (size_t)(BATCH + gie) * HID;
    float ss = 0.f;
    #pragma unroll
    for (int nf = 0; nf < 8; ++nf) {
      const int n = nf * 16 + ln;
      float h = acc[nf][e] + amr[n] + abr[n] + b1v[nf];
      h = h > 0.f ? h : SLOPE * h;
      ss = fmaf(h, wv[nf], ss);
    }
    ss += __shfl_xor(ss, 1);
    ss += __shfl_xor(ss, 2);
    ss += __shfl_xor(ss, 4);
    ss += __shfl_xor(ss, 8);
    if (ln == 0) {
      const int gb = rowe / N_ANTS, ga = rowe - gb * N_ANTS;
      out[(size_t)gb * (N_ANTS + 1) + 1 + ga] = rough[rowe] + ss + bo;
    }
  }
  if (tid == 0) {   // EPSILON dummy column (duplicate same-value writes benign)
    const int g0 = (mb * 64) / N_ANTS;
    int g1 = (mb * 64 + 63) / N_ANTS;
    if (g1 > BATCH - 1) g1 = BATCH - 1;
    for (int g = g0; g <= g1; ++g) out[(size_t)g * (N_ANTS + 1)] = EPS_VAL;
  }
}

// ---- fallback (exact f32, used only if workspace too small) -----------------
__global__ void k_eps(float* __restrict__ out) {
  out[(size_t)threadIdx.x * (N_ANTS + 1)] = EPS_VAL;
}

__global__ __launch_bounds__(128) void k_fb(const float* __restrict__ all_m,
                                            const float* __restrict__ men,
                                            const float* __restrict__ pw,
                                            const int*   __restrict__ topi,
                                            const float* __restrict__ rough,
                                            const float* __restrict__ w1,
                                            const float* __restrict__ b1,
                                            const float* __restrict__ wout,
                                            const float* __restrict__ bout,
                                            float* __restrict__ out) {
  __shared__ float xs[IN_F];
  __shared__ float hred[HID];
  const int pair = blockIdx.x;
  const int t = threadIdx.x;
  const int bb = pair / N_ANTS;
  const int idx = topi[pair];
  const float* pA = men + (size_t)bb * EMB;
  const float* pB = all_m + (size_t)idx * EMB;
  for (int k = t; k < EMB; k += 128) {
    float a = pA[k], b = pB[k];
    xs[k] = a; xs[EMB + k] = b; xs[2 * EMB + k] = a * b;
  }
  if (t < PW_EMB) xs[3 * EMB + t] = pw[(size_t)pair * PW_EMB + t];
  __syncthreads();
  float acc = 0.f;
  for (int k = 0; k < IN_F; ++k) acc = fmaf(xs[k], w1[(size_t)k * HID + t], acc);
  acc += b1[t];
  acc = acc > 0.f ? acc : SLOPE * acc;
  hred[t] = acc * wout[t];
  __syncthreads();
  for (int off = 64; off > 0; off >>= 1) {
    if (t < off) hred[t] += hred[t + off];
    __syncthreads();
  }
  if (t == 0)
    out[(size_t)bb * (N_ANTS + 1) + 1 + (pair - bb * N_ANTS)] = rough[pair] + hred[0] + bout[0];
}

extern "C" void kernel_launch(void* const* d_in, const int* in_sizes, int n_in,
                              void* d_out, int out_size, void* d_ws, size_t ws_size,
                              hipStream_t stream) {
  const float* all_m = (const float*)d_in[0];
  const float* men   = (const float*)d_in[1];
  const float* pw    = (const float*)d_in[2];
  const int*   topi  = (const int*)  d_in[3];
  const float* rough = (const float*)d_in[4];
  const float* w1    = (const float*)d_in[5];
  const float* b1    = (const float*)d_in[6];
  const float* wout  = (const float*)d_in[7];
  const float* bout  = (const float*)d_in[8];
  float* out = (float*)d_out;

  const size_t CNT_BYTES  = 256;                                              // counter slab
  const size_t W1F_BYTES  = (size_t)HID * IN_F * sizeof(unsigned short);      // 802816
  const size_t AMAB_BYTES = (size_t)AMAB_ROWS * HID * sizeof(float);          // 5382144

  if (ws_size >= CNT_BYTES + W1F_BYTES + AMAB_BYTES) {
    unsigned* cnt = (unsigned*)d_ws;
    unsigned short* w1f = (unsigned short*)((char*)d_ws + CNT_BYTES);
    float* amab = (float*)((char*)d_ws + CNT_BYTES + W1F_BYTES);
    hipMemsetAsync(d_ws, 0, 8, stream);   // zero the join counter each launch
    k_convert<<<196, 256, 0, stream>>>(w1, w1f);
    k_fused<<<TOT_BLK, 256, 0, stream>>>(all_m, men, pw, topi, rough, w1f, amab,
                                         b1, wout, bout, out, cnt);
  } else {
    k_eps<<<1, BATCH, 0, stream>>>(out);
    k_fb<<<M_TOT, 128, 0, stream>>>(all_m, men, pw, topi, rough, w1, b1, wout, bout, out);
  }
}

// Round 5
// 101.832 us; speedup vs baseline: 1.3749x; 1.3749x over previous
//
#include <hip/hip_runtime.h>

#define N_MENT   10000
#define BATCH    512
#define N_ANTS   50
#define EMB      1024
#define PW_EMB   64
#define IN_F     3136       // 3*EMB + PW_EMB
#define HID      128
#define M_TOT    (BATCH * N_ANTS)   // 25600
#define EPS_VAL  1e-7f
#define SLOPE    0.01f
#define NKT      98         // IN_F / 32 k-tiles

#define AMAB_ROWS  (BATCH + N_MENT)              // 10512
#define AMAB_BLK   (16 + (N_MENT + 31) / 32)     // 16 AM-blocks + 313 AB-blocks = 329
#define MAIN_BLK   (M_TOT / 32)                  // 800
#define TOT_BLK    (AMAB_BLK + MAIN_BLK)         // 1129  (capacity 5/CU*256 = 1280)

using f32x4 = __attribute__((ext_vector_type(4))) float;
using s16x8 = __attribute__((ext_vector_type(8))) short;
using u16x8 = __attribute__((ext_vector_type(8))) unsigned short;

__device__ __forceinline__ unsigned short f2bf(float f) {
  unsigned u = __builtin_bit_cast(unsigned, f);
  u += 0x7FFFu + ((u >> 16) & 1u);   // RNE
  return (unsigned short)(u >> 16);
}

// pack 8 f32 -> 8 bf16 (RNE) via v_cvt_pk_bf16_f32 (verified bit-equal in R4)
__device__ __forceinline__ u16x8 pack8(float4 lo, float4 hi) {
  union { u16x8 v; unsigned u[4]; } r;
  asm("v_cvt_pk_bf16_f32 %0, %1, %2" : "=v"(r.u[0]) : "v"(lo.x), "v"(lo.y));
  asm("v_cvt_pk_bf16_f32 %0, %1, %2" : "=v"(r.u[1]) : "v"(lo.z), "v"(lo.w));
  asm("v_cvt_pk_bf16_f32 %0, %1, %2" : "=v"(r.u[2]) : "v"(hi.x), "v"(hi.y));
  asm("v_cvt_pk_bf16_f32 %0, %1, %2" : "=v"(r.u[3]) : "v"(hi.z), "v"(hi.w));
  return r.v;
}

// ---- kernel 0: W1 [3136][128] f32 -> w1f in MFMA B-fragment-linear order ----
// w1f element index = ((tn*NKT + tk)*64 + lane)*8 + j
//   lane = ln + lg*16 holds B[col = tn*16+ln][k = tk*32 + lg*8 + j]
__global__ __launch_bounds__(256) void k_convert(const float* __restrict__ w1,
                                                 unsigned short* __restrict__ w1f) {
  const int id   = blockIdx.x * 256 + threadIdx.x;   // 0..50175
  const int lane = id & 63;
  const int tile = id >> 6;                          // 0..783 = 8*98
  const int tk   = tile % NKT, tn = tile / NKT;
  const int n    = tn * 16 + (lane & 15);
  const int k    = tk * 32 + (lane >> 4) * 8;
  u16x8 o;
  #pragma unroll
  for (int j = 0; j < 8; ++j) o[j] = f2bf(w1[(size_t)(k + j) * HID + n]);
  *(u16x8*)(w1f + (size_t)id * 8) = o;
}

// ---- fused kernel: amab-role blocks + main-role blocks, spin-joined ---------
// Inner loops are the R3-proven low-pressure structure (LDS X-staging, one
// barrier per K-step, depth-1 B-fragment register prefetch, VGPR ~60).
__global__ __launch_bounds__(256, 5) void k_fused(
    const float* __restrict__ all_m, const float* __restrict__ men,
    const float* __restrict__ pw, const int* __restrict__ topi,
    const float* __restrict__ rough, const unsigned short* __restrict__ w1f,
    float* __restrict__ amab, const float* __restrict__ b1,
    const float* __restrict__ wout, const float* __restrict__ bout,
    float* __restrict__ out, unsigned* __restrict__ cnt) {
  __shared__ __align__(16) unsigned short Xs[2][32 * 72];
  __shared__ float red[4 * 32];

  const int t    = threadIdx.x;
  const int bid  = blockIdx.x;
  const int lane = t & 63, wid = t >> 6;
  const int ln   = lane & 15, lg = lane >> 4;
  const int wcol = wid * 32;
  const unsigned short* wf0 = w1f + (((size_t)(wid * 2)     * NKT) * 64 + lane) * 8;
  const unsigned short* wf1 = w1f + (((size_t)(wid * 2 + 1) * NKT) * 64 + lane) * 8;
  const int sr = t >> 3, sq = t & 7;

  if (bid < AMAB_BLK) {
    // ================= role A: AM/AB precompute (R3 k_amab) ================
    const bool isAM   = (bid < 16);
    const int base    = isAM ? bid * 32 : (bid - 16) * 32;
    const int nrows   = isAM ? BATCH : N_MENT;
    const int tkbase  = isAM ? 0 : 32;
    const float* src  = isAM ? men : all_m;
    const int outbase = isAM ? base : BATCH + base;

    const int srow = (base + sr < nrows) ? base + sr : nrows - 1;
    const float* pX = src + (size_t)srow * EMB + sq * 8;

    f32x4 acc[2][2] = {};
    float4 r0 = ((const float4*)pX)[0];
    float4 r1 = ((const float4*)pX)[1];
    s16x8 bc00 = *(const s16x8*)(wf0 + (size_t)(tkbase)     * 512);
    s16x8 bc01 = *(const s16x8*)(wf1 + (size_t)(tkbase)     * 512);
    s16x8 bc10 = *(const s16x8*)(wf0 + (size_t)(tkbase + 1) * 512);
    s16x8 bc11 = *(const s16x8*)(wf1 + (size_t)(tkbase + 1) * 512);

    int buf = 0;
    for (int s = 0; s < 16; ++s) {
      *(u16x8*)&Xs[buf][sr * 72 + sq * 8] = pack8(r0, r1);
      if (s < 15) {
        const float* q = pX + (s + 1) * 64;
        r0 = ((const float4*)q)[0];
        r1 = ((const float4*)q)[1];
      }
      const int tkn = tkbase + (s < 15 ? (s + 1) : s) * 2;
      s16x8 bn00 = *(const s16x8*)(wf0 + (size_t)(tkn)     * 512);
      s16x8 bn01 = *(const s16x8*)(wf1 + (size_t)(tkn)     * 512);
      s16x8 bn10 = *(const s16x8*)(wf0 + (size_t)(tkn + 1) * 512);
      s16x8 bn11 = *(const s16x8*)(wf1 + (size_t)(tkn + 1) * 512);

      __syncthreads();
      #pragma unroll
      for (int mf = 0; mf < 2; ++mf) {
        s16x8 a0 = *(const s16x8*)&Xs[buf][(mf * 16 + ln) * 72 + lg * 8];
        s16x8 a1 = *(const s16x8*)&Xs[buf][(mf * 16 + ln) * 72 + 32 + lg * 8];
        acc[mf][0] = __builtin_amdgcn_mfma_f32_16x16x32_bf16(a0, bc00, acc[mf][0], 0, 0, 0);
        acc[mf][1] = __builtin_amdgcn_mfma_f32_16x16x32_bf16(a0, bc01, acc[mf][1], 0, 0, 0);
        acc[mf][0] = __builtin_amdgcn_mfma_f32_16x16x32_bf16(a1, bc10, acc[mf][0], 0, 0, 0);
        acc[mf][1] = __builtin_amdgcn_mfma_f32_16x16x32_bf16(a1, bc11, acc[mf][1], 0, 0, 0);
      }
      bc00 = bn00; bc01 = bn01; bc10 = bn10; bc11 = bn11;
      buf ^= 1;
    }
    #pragma unroll
    for (int mf = 0; mf < 2; ++mf)
      #pragma unroll
      for (int e = 0; e < 4; ++e) {
        const int r = mf * 16 + lg * 4 + e;
        if (base + r < nrows) {
          amab[(size_t)(outbase + r) * HID + wcol + ln]      = acc[mf][0][e];
          amab[(size_t)(outbase + r) * HID + wcol + 16 + ln] = acc[mf][1][e];
        }
      }
    __threadfence();          // release amab stores device-wide
    __syncthreads();          // all waves of block done before signaling
    if (t == 0)
      __hip_atomic_fetch_add(&cnt[0], 1u, __ATOMIC_RELEASE, __HIP_MEMORY_SCOPE_AGENT);
    return;
  }

  // =================== role B: main fused GEMM (R3 k_main) =================
  const int mb = bid - AMAB_BLK;            // 0..799
  const int m0 = mb * 32;

  const int m  = m0 + sr;
  const int bb = m / N_ANTS;
  const int bidx = topi[m];
  const float* pA = men   + (size_t)bb   * EMB    + sq * 8;
  const float* pB = all_m + (size_t)bidx * EMB    + sq * 8;
  const float* pP = pw    + (size_t)m    * PW_EMB + sq * 8;

  f32x4 acc[2][2] = {};

  float4 ra0 = ((const float4*)pA)[0];
  float4 ra1 = ((const float4*)pA)[1];
  float4 rb0 = ((const float4*)pB)[0];
  float4 rb1 = ((const float4*)pB)[1];
  s16x8 bc00 = *(const s16x8*)(wf0 + (size_t)(64)     * 512);
  s16x8 bc01 = *(const s16x8*)(wf1 + (size_t)(64)     * 512);
  s16x8 bc10 = *(const s16x8*)(wf0 + (size_t)(64 + 1) * 512);
  s16x8 bc11 = *(const s16x8*)(wf1 + (size_t)(64 + 1) * 512);

  int buf = 0;
  // 16 similarity steps (k=2048..3071) + 1 pw step (k=3072..3135), BK=64 each.
  for (int s = 0; s < 17; ++s) {
    float4 plo = make_float4(ra0.x * rb0.x, ra0.y * rb0.y, ra0.z * rb0.z, ra0.w * rb0.w);
    float4 phi = make_float4(ra1.x * rb1.x, ra1.y * rb1.y, ra1.z * rb1.z, ra1.w * rb1.w);
    *(u16x8*)&Xs[buf][sr * 72 + sq * 8] = pack8(plo, phi);

    if (s < 15) {                       // prefetch next similarity step
      const float* qA = pA + (s + 1) * 64;
      const float* qB = pB + (s + 1) * 64;
      ra0 = ((const float4*)qA)[0]; ra1 = ((const float4*)qA)[1];
      rb0 = ((const float4*)qB)[0]; rb1 = ((const float4*)qB)[1];
    } else if (s == 15) {               // prefetch pw step; multiply by 1.0
      ra0 = ((const float4*)pP)[0];  ra1 = ((const float4*)pP)[1];
      rb0 = make_float4(1.f, 1.f, 1.f, 1.f); rb1 = rb0;
    }
    const int tkn = 64 + (s < 16 ? (s + 1) : s) * 2;   // B-frag prefetch (clamped)
    s16x8 bn00 = *(const s16x8*)(wf0 + (size_t)(tkn)     * 512);
    s16x8 bn01 = *(const s16x8*)(wf1 + (size_t)(tkn)     * 512);
    s16x8 bn10 = *(const s16x8*)(wf0 + (size_t)(tkn + 1) * 512);
    s16x8 bn11 = *(const s16x8*)(wf1 + (size_t)(tkn + 1) * 512);

    __syncthreads();
    #pragma unroll
    for (int mf = 0; mf < 2; ++mf) {
      s16x8 a0 = *(const s16x8*)&Xs[buf][(mf * 16 + ln) * 72 + lg * 8];
      s16x8 a1 = *(const s16x8*)&Xs[buf][(mf * 16 + ln) * 72 + 32 + lg * 8];
      acc[mf][0] = __builtin_amdgcn_mfma_f32_16x16x32_bf16(a0, bc00, acc[mf][0], 0, 0, 0);
      acc[mf][1] = __builtin_amdgcn_mfma_f32_16x16x32_bf16(a0, bc01, acc[mf][1], 0, 0, 0);
      acc[mf][0] = __builtin_amdgcn_mfma_f32_16x16x32_bf16(a1, bc10, acc[mf][0], 0, 0, 0);
      acc[mf][1] = __builtin_amdgcn_mfma_f32_16x16x32_bf16(a1, bc11, acc[mf][1], 0, 0, 0);
    }
    bc00 = bn00; bc01 = bn01; bc10 = bn10; bc11 = bn11;
    buf ^= 1;
  }

  // wait for amab role (all 1129 blocks co-resident: launch_bounds(256,5))
  if (t == 0) {
    while (__hip_atomic_load(&cnt[0], __ATOMIC_ACQUIRE, __HIP_MEMORY_SCOPE_AGENT)
           < (unsigned)AMAB_BLK)
      __builtin_amdgcn_s_sleep(2);
  }
  __syncthreads();

  // epilogue: + AM[bb] + AB[idx] + b1, leaky, dot W_out, reduce over n
  const int n0 = wcol + ln, n1 = wcol + 16 + ln;
  const float bias0 = b1[n0], bias1 = b1[n1];
  const float w_0 = wout[n0], w_1 = wout[n1];
  #pragma unroll
  for (int mf = 0; mf < 2; ++mf)
    #pragma unroll
    for (int e = 0; e < 4; ++e) {
      const int ml = mf * 16 + lg * 4 + e;
      const int gm = m0 + ml;
      const int gb = gm / N_ANTS;
      const int gi = topi[gm];
      const float* amr = amab + (size_t)gb * HID;
      const float* abr = amab + (size_t)(BATCH + gi) * HID;
      float h0 = acc[mf][0][e] + amr[n0] + abr[n0] + bias0;
      float h1 = acc[mf][1][e] + amr[n1] + abr[n1] + bias1;
      h0 = h0 > 0.f ? h0 : SLOPE * h0;
      h1 = h1 > 0.f ? h1 : SLOPE * h1;
      float ss = h0 * w_0 + h1 * w_1;
      ss += __shfl_xor(ss, 1);
      ss += __shfl_xor(ss, 2);
      ss += __shfl_xor(ss, 4);
      ss += __shfl_xor(ss, 8);
      if (ln == 0) red[wid * 32 + ml] = ss;
    }
  __syncthreads();
  if (t < 32) {
    const int gm = m0 + t;
    const int gb = gm / N_ANTS;
    const int ga = gm - gb * N_ANTS;
    out[(size_t)gb * (N_ANTS + 1) + 1 + ga] =
        rough[gm] + red[t] + red[32 + t] + red[64 + t] + red[96 + t] + bout[0];
  }
  if (t == 0) {   // EPSILON dummy column (duplicate same-value writes benign)
    for (int g = m0 / N_ANTS; g <= (m0 + 31) / N_ANTS; ++g)
      out[(size_t)g * (N_ANTS + 1)] = EPS_VAL;
  }
}

// ---- fallback (exact f32, used only if workspace too small) -----------------
__global__ void k_eps(float* __restrict__ out) {
  out[(size_t)threadIdx.x * (N_ANTS + 1)] = EPS_VAL;
}

__global__ __launch_bounds__(128) void k_fb(const float* __restrict__ all_m,
                                            const float* __restrict__ men,
                                            const float* __restrict__ pw,
                                            const int*   __restrict__ topi,
                                            const float* __restrict__ rough,
                                            const float* __restrict__ w1,
                                            const float* __restrict__ b1,
                                            const float* __restrict__ wout,
                                            const float* __restrict__ bout,
                                            float* __restrict__ out) {
  __shared__ float xs[IN_F];
  __shared__ float hred[HID];
  const int pair = blockIdx.x;
  const int t = threadIdx.x;
  const int bb = pair / N_ANTS;
  const int idx = topi[pair];
  const float* pA = men + (size_t)bb * EMB;
  const float* pB = all_m + (size_t)idx * EMB;
  for (int k = t; k < EMB; k += 128) {
    float a = pA[k], b = pB[k];
    xs[k] = a; xs[EMB + k] = b; xs[2 * EMB + k] = a * b;
  }
  if (t < PW_EMB) xs[3 * EMB + t] = pw[(size_t)pair * PW_EMB + t];
  __syncthreads();
  float acc = 0.f;
  for (int k = 0; k < IN_F; ++k) acc = fmaf(xs[k], w1[(size_t)k * HID + t], acc);
  acc += b1[t];
  acc = acc > 0.f ? acc : SLOPE * acc;
  hred[t] = acc * wout[t];
  __syncthreads();
  for (int off = 64; off > 0; off >>= 1) {
    if (t < off) hred[t] += hred[t + off];
    __syncthreads();
  }
  if (t == 0)
    out[(size_t)bb * (N_ANTS + 1) + 1 + (pair - bb * N_ANTS)] = rough[pair] + hred[0] + bout[0];
}

extern "C" void kernel_launch(void* const* d_in, const int* in_sizes, int n_in,
                              void* d_out, int out_size, void* d_ws, size_t ws_size,
                              hipStream_t stream) {
  const float* all_m = (const float*)d_in[0];
  const float* men   = (const float*)d_in[1];
  const float* pw    = (const float*)d_in[2];
  const int*   topi  = (const int*)  d_in[3];
  const float* rough = (const float*)d_in[4];
  const float* w1    = (const float*)d_in[5];
  const float* b1    = (const float*)d_in[6];
  const float* wout  = (const float*)d_in[7];
  const float* bout  = (const float*)d_in[8];
  float* out = (float*)d_out;

  const size_t CNT_BYTES  = 256;
  const size_t W1F_BYTES  = (size_t)HID * IN_F * sizeof(unsigned short);      // 802816
  const size_t AMAB_BYTES = (size_t)AMAB_ROWS * HID * sizeof(float);          // 5382144

  if (ws_size >= CNT_BYTES + W1F_BYTES + AMAB_BYTES) {
    unsigned* cnt = (unsigned*)d_ws;
    unsigned short* w1f = (unsigned short*)((char*)d_ws + CNT_BYTES);
    float* amab = (float*)((char*)d_ws + CNT_BYTES + W1F_BYTES);
    hipMemsetAsync(d_ws, 0, 8, stream);   // zero join counter every launch
    k_convert<<<196, 256, 0, stream>>>(w1, w1f);
    k_fused<<<TOT_BLK, 256, 0, stream>>>(all_m, men, pw, topi, rough, w1f, amab,
                                         b1, wout, bout, out, cnt);
  } else {
    k_eps<<<1, BATCH, 0, stream>>>(out);
    k_fb<<<M_TOT, 128, 0, stream>>>(all_m, men, pw, topi, rough, w1, b1, wout, bout, out);
  }
}

// Round 6
// 75.846 us; speedup vs baseline: 1.8459x; 1.3426x over previous
//
#include <hip/hip_runtime.h>

#define N_MENT   10000
#define BATCH    512
#define N_ANTS   50
#define EMB      1024
#define PW_EMB   64
#define IN_F     3136       // 3*EMB + PW_EMB
#define HID      128
#define M_TOT    (BATCH * N_ANTS)   // 25600
#define EPS_VAL  1e-7f
#define SLOPE    0.01f

// main GEMM covers W1 rows [1024, 3136): b(1024) + sim(1024) + pw(64) = 2112
#define NKT_M    66         // 2112 / 32 k-tiles (permuted order, see below)
#define CONV_BLK 132        // 8 tn * 66 tk tiles * 64 lanes / 256 threads
#define AM_BLK   128        // 512 rows / 4 rows per block
#define MAIN_BLK (M_TOT / 32)   // 800

using f32x4 = __attribute__((ext_vector_type(4))) float;
using s16x8 = __attribute__((ext_vector_type(8))) short;
using u16x8 = __attribute__((ext_vector_type(8))) unsigned short;

__device__ __forceinline__ unsigned short f2bf(float f) {
  unsigned u = __builtin_bit_cast(unsigned, f);
  u += 0x7FFFu + ((u >> 16) & 1u);   // RNE
  return (unsigned short)(u >> 16);
}

// pack 8 f32 -> 8 bf16 (RNE) via v_cvt_pk_bf16_f32 (bit-equal to f2bf, verified R4/R5)
__device__ __forceinline__ u16x8 pack8(float4 lo, float4 hi) {
  union { u16x8 v; unsigned u[4]; } r;
  asm("v_cvt_pk_bf16_f32 %0, %1, %2" : "=v"(r.u[0]) : "v"(lo.x), "v"(lo.y));
  asm("v_cvt_pk_bf16_f32 %0, %1, %2" : "=v"(r.u[1]) : "v"(lo.z), "v"(lo.w));
  asm("v_cvt_pk_bf16_f32 %0, %1, %2" : "=v"(r.u[2]) : "v"(hi.x), "v"(hi.y));
  asm("v_cvt_pk_bf16_f32 %0, %1, %2" : "=v"(r.u[3]) : "v"(hi.z), "v"(hi.w));
  return r.v;
}

// permuted k-tile -> original W1 row base.  For chunk c = tk>>2, r = tk&3:
//   r=0,1 -> b-region   row 1024 + c*64 + r*32
//   r=2,3 -> sim-region row 2048 + c*64 + (r-2)*32
//   tk 64,65 -> pw rows 3072 + (tk-64)*32
__device__ __forceinline__ int tile_orig_k(int tk) {
  if (tk >= 64) return 3072 + (tk - 64) * 32;
  const int c = tk >> 2, r = tk & 3;
  return (r < 2) ? (1024 + c * 64 + r * 32) : (2048 + c * 64 + (r - 2) * 32);
}

// ---- kernel 1: convert-role (W1 rows [1024,3136) -> w1f frags)  ||  AM-role --
// w1f element index = ((tn*NKT_M + tk)*64 + lane)*8 + j
//   lane = ln + lg*16 holds B[col = tn*16+ln][k = orig_k(tk) + lg*8 + j]
// AM[b][n] = sum_k men[b][k] * W1[k][n]  for k in [0,1024)  (exact f32)
__global__ __launch_bounds__(256) void k_prep(const float* __restrict__ w1,
                                              const float* __restrict__ men,
                                              unsigned short* __restrict__ w1f,
                                              float* __restrict__ am) {
  const int bid = blockIdx.x;
  if (bid < CONV_BLK) {
    const int id   = bid * 256 + threadIdx.x;   // 0..33791
    const int lane = id & 63;
    const int tile = id >> 6;                   // 0..527 = tn*66 + tk
    const int tk   = tile % NKT_M, tn = tile / NKT_M;
    const int n    = tn * 16 + (lane & 15);
    const int k    = tile_orig_k(tk) + (lane >> 4) * 8;
    u16x8 o;
    #pragma unroll
    for (int j = 0; j < 8; ++j) o[j] = f2bf(w1[(size_t)(k + j) * HID + n]);
    *(u16x8*)(w1f + (size_t)id * 8) = o;
    return;
  }
  // ---- AM role: 4 batch-rows per block, vector f32 from raw W1 -------------
  __shared__ float mr[4][EMB];
  const int t  = threadIdx.x;
  const int r0 = (bid - CONV_BLK) * 4;
  {
    const float4* src = (const float4*)(men + (size_t)r0 * EMB);
    float4* dst = (float4*)&mr[0][0];
    #pragma unroll
    for (int i = 0; i < 4; ++i) dst[t + i * 256] = src[t + i * 256];
  }
  __syncthreads();
  const int cc = t & 127, half = t >> 7;     // cols 0..127; rows r0+2h, r0+2h+1
  const float* wp = w1 + cc;
  const float* a0 = mr[2 * half];
  const float* a1 = mr[2 * half + 1];
  float acc0 = 0.f, acc1 = 0.f;
  #pragma unroll 8
  for (int k = 0; k < EMB; ++k) {
    const float w = wp[(size_t)k * HID];
    acc0 = fmaf(w, a0[k], acc0);
    acc1 = fmaf(w, a1[k], acc1);
  }
  am[(size_t)(r0 + 2 * half)     * HID + cc] = acc0;
  am[(size_t)(r0 + 2 * half + 1) * HID + cc] = acc1;
}

// ---- kernel 2: main fused GEMM, K = 2112 (b | a*b | pw), BM=32 --------------
// Per chunk c: one set of a/b row loads feeds TWO LDS tiles (X=b, X=a*b);
// one barrier per chunk, 16 MFMA per wave per chunk. W-frags for the chunk
// are register-loaded BEFORE the barrier (L2 latency hides under MFMA phase).
__global__ __launch_bounds__(256) void k_main(
    const float* __restrict__ all_m, const float* __restrict__ men,
    const float* __restrict__ pw, const int* __restrict__ topi,
    const float* __restrict__ rough, const unsigned short* __restrict__ w1f,
    const float* __restrict__ am, const float* __restrict__ b1,
    const float* __restrict__ wout, const float* __restrict__ bout,
    float* __restrict__ out) {
  __shared__ __align__(16) unsigned short Xs[2][2][32 * 72];
  __shared__ float red[4 * 32];

  const int t  = threadIdx.x;
  const int m0 = blockIdx.x * 32;

  const int sr = t >> 3, sq = t & 7;          // staging: row sr, 8-col group sq
  const int m  = m0 + sr;
  const int bb = m / N_ANTS;
  const int bidx = topi[m];
  const float* pA = men   + (size_t)bb   * EMB    + sq * 8;
  const float* pB = all_m + (size_t)bidx * EMB    + sq * 8;
  const float* pP = pw    + (size_t)m    * PW_EMB + sq * 8;

  const int lane = t & 63, wid = t >> 6;
  const int ln = lane & 15, lg = lane >> 4;
  const int wcol = wid * 32;
  const unsigned short* wfA = w1f + ((size_t)(2 * wid)     * NKT_M * 64 + lane) * 8;
  const unsigned short* wfB = w1f + ((size_t)(2 * wid + 1) * NKT_M * 64 + lane) * 8;

  f32x4 acc[2][2] = {};

  float4 a0 = ((const float4*)pA)[0], a1 = ((const float4*)pA)[1];
  float4 b0 = ((const float4*)pB)[0], b1v = ((const float4*)pB)[1];

  int buf = 0;
  for (int c = 0; c < 16; ++c) {
    // stage both tiles: tile0 = b values, tile1 = a*b
    *(u16x8*)&Xs[buf][0][sr * 72 + sq * 8] = pack8(b0, b1v);
    float4 s0 = make_float4(a0.x * b0.x,  a0.y * b0.y,  a0.z * b0.z,  a0.w * b0.w);
    float4 s1 = make_float4(a1.x * b1v.x, a1.y * b1v.y, a1.z * b1v.z, a1.w * b1v.w);
    *(u16x8*)&Xs[buf][1][sr * 72 + sq * 8] = pack8(s0, s1);

    // prefetch next chunk's a/b rows (or pw at the end)
    if (c < 15) {
      const float* qA = pA + (c + 1) * 64;
      const float* qB = pB + (c + 1) * 64;
      a0 = ((const float4*)qA)[0]; a1 = ((const float4*)qA)[1];
      b0 = ((const float4*)qB)[0]; b1v = ((const float4*)qB)[1];
    } else {
      a0 = ((const float4*)pP)[0]; a1 = ((const float4*)pP)[1];
    }

    // load this chunk's 8 W-fragments into registers before the barrier
    s16x8 wr[8];
    #pragma unroll
    for (int half = 0; half < 2; ++half)
      #pragma unroll
      for (int ks = 0; ks < 2; ++ks) {
        const size_t tk = (size_t)(c * 4 + half * 2 + ks) * 512;
        wr[(half * 2 + ks) * 2]     = *(const s16x8*)(wfA + tk);
        wr[(half * 2 + ks) * 2 + 1] = *(const s16x8*)(wfB + tk);
      }

    __syncthreads();
    #pragma unroll
    for (int half = 0; half < 2; ++half)
      #pragma unroll
      for (int ks = 0; ks < 2; ++ks) {
        s16x8 x0 = *(const s16x8*)&Xs[buf][half][ln * 72        + ks * 32 + lg * 8];
        s16x8 x1 = *(const s16x8*)&Xs[buf][half][(16 + ln) * 72 + ks * 32 + lg * 8];
        const s16x8 w0 = wr[(half * 2 + ks) * 2];
        const s16x8 w1r = wr[(half * 2 + ks) * 2 + 1];
        acc[0][0] = __builtin_amdgcn_mfma_f32_16x16x32_bf16(x0, w0,  acc[0][0], 0, 0, 0);
        acc[0][1] = __builtin_amdgcn_mfma_f32_16x16x32_bf16(x0, w1r, acc[0][1], 0, 0, 0);
        acc[1][0] = __builtin_amdgcn_mfma_f32_16x16x32_bf16(x1, w0,  acc[1][0], 0, 0, 0);
        acc[1][1] = __builtin_amdgcn_mfma_f32_16x16x32_bf16(x1, w1r, acc[1][1], 0, 0, 0);
      }
    buf ^= 1;
  }

  // pw chunk: a0/a1 hold pw values; tiles 64,65
  *(u16x8*)&Xs[buf][0][sr * 72 + sq * 8] = pack8(a0, a1);
  {
    s16x8 wr[4];
    #pragma unroll
    for (int ks = 0; ks < 2; ++ks) {
      const size_t tk = (size_t)(64 + ks) * 512;
      wr[ks * 2]     = *(const s16x8*)(wfA + tk);
      wr[ks * 2 + 1] = *(const s16x8*)(wfB + tk);
    }
    __syncthreads();
    #pragma unroll
    for (int ks = 0; ks < 2; ++ks) {
      s16x8 x0 = *(const s16x8*)&Xs[buf][0][ln * 72        + ks * 32 + lg * 8];
      s16x8 x1 = *(const s16x8*)&Xs[buf][0][(16 + ln) * 72 + ks * 32 + lg * 8];
      acc[0][0] = __builtin_amdgcn_mfma_f32_16x16x32_bf16(x0, wr[ks * 2],     acc[0][0], 0, 0, 0);
      acc[0][1] = __builtin_amdgcn_mfma_f32_16x16x32_bf16(x0, wr[ks * 2 + 1], acc[0][1], 0, 0, 0);
      acc[1][0] = __builtin_amdgcn_mfma_f32_16x16x32_bf16(x1, wr[ks * 2],     acc[1][0], 0, 0, 0);
      acc[1][1] = __builtin_amdgcn_mfma_f32_16x16x32_bf16(x1, wr[ks * 2 + 1], acc[1][1], 0, 0, 0);
    }
  }

  // epilogue: + AM[bb] + b1, leaky, dot W_out, reduce over n
  const int n0 = wcol + ln, n1 = wcol + 16 + ln;
  const float bias0 = b1[n0], bias1 = b1[n1];
  const float w_0 = wout[n0], w_1 = wout[n1];
  #pragma unroll
  for (int mf = 0; mf < 2; ++mf)
    #pragma unroll
    for (int e = 0; e < 4; ++e) {
      const int ml = mf * 16 + lg * 4 + e;
      const int gm = m0 + ml;
      const int gb = gm / N_ANTS;
      const float* amr = am + (size_t)gb * HID;
      float h0 = acc[mf][0][e] + amr[n0] + bias0;
      float h1 = acc[mf][1][e] + amr[n1] + bias1;
      h0 = h0 > 0.f ? h0 : SLOPE * h0;
      h1 = h1 > 0.f ? h1 : SLOPE * h1;
      float ss = h0 * w_0 + h1 * w_1;
      ss += __shfl_xor(ss, 1);
      ss += __shfl_xor(ss, 2);
      ss += __shfl_xor(ss, 4);
      ss += __shfl_xor(ss, 8);
      if (ln == 0) red[wid * 32 + ml] = ss;
    }
  __syncthreads();
  if (t < 32) {
    const int gm = m0 + t;
    const int gb = gm / N_ANTS;
    const int ga = gm - gb * N_ANTS;
    out[(size_t)gb * (N_ANTS + 1) + 1 + ga] =
        rough[gm] + red[t] + red[32 + t] + red[64 + t] + red[96 + t] + bout[0];
  }
  if (t == 0) {   // EPSILON dummy column (duplicate same-value writes benign)
    for (int g = m0 / N_ANTS; g <= (m0 + 31) / N_ANTS; ++g)
      out[(size_t)g * (N_ANTS + 1)] = EPS_VAL;
  }
}

// ---- fallback (exact f32, used only if workspace too small) -----------------
__global__ void k_eps(float* __restrict__ out) {
  out[(size_t)threadIdx.x * (N_ANTS + 1)] = EPS_VAL;
}

__global__ __launch_bounds__(128) void k_fb(const float* __restrict__ all_m,
                                            const float* __restrict__ men,
                                            const float* __restrict__ pw,
                                            const int*   __restrict__ topi,
                                            const float* __restrict__ rough,
                                            const float* __restrict__ w1,
                                            const float* __restrict__ b1,
                                            const float* __restrict__ wout,
                                            const float* __restrict__ bout,
                                            float* __restrict__ out) {
  __shared__ float xs[IN_F];
  __shared__ float hred[HID];
  const int pair = blockIdx.x;
  const int t = threadIdx.x;
  const int bb = pair / N_ANTS;
  const int idx = topi[pair];
  const float* pA = men + (size_t)bb * EMB;
  const float* pB = all_m + (size_t)idx * EMB;
  for (int k = t; k < EMB; k += 128) {
    float a = pA[k], b = pB[k];
    xs[k] = a; xs[EMB + k] = b; xs[2 * EMB + k] = a * b;
  }
  if (t < PW_EMB) xs[3 * EMB + t] = pw[(size_t)pair * PW_EMB + t];
  __syncthreads();
  float acc = 0.f;
  for (int k = 0; k < IN_F; ++k) acc = fmaf(xs[k], w1[(size_t)k * HID + t], acc);
  acc += b1[t];
  acc = acc > 0.f ? acc : SLOPE * acc;
  hred[t] = acc * wout[t];
  __syncthreads();
  for (int off = 64; off > 0; off >>= 1) {
    if (t < off) hred[t] += hred[t + off];
    __syncthreads();
  }
  if (t == 0)
    out[(size_t)bb * (N_ANTS + 1) + 1 + (pair - bb * N_ANTS)] = rough[pair] + hred[0] + bout[0];
}

extern "C" void kernel_launch(void* const* d_in, const int* in_sizes, int n_in,
                              void* d_out, int out_size, void* d_ws, size_t ws_size,
                              hipStream_t stream) {
  const float* all_m = (const float*)d_in[0];
  const float* men   = (const float*)d_in[1];
  const float* pw    = (const float*)d_in[2];
  const int*   topi  = (const int*)  d_in[3];
  const float* rough = (const float*)d_in[4];
  const float* w1    = (const float*)d_in[5];
  const float* b1    = (const float*)d_in[6];
  const float* wout  = (const float*)d_in[7];
  const float* bout  = (const float*)d_in[8];
  float* out = (float*)d_out;

  const size_t W1F_BYTES = (size_t)8 * NKT_M * 64 * 8 * sizeof(unsigned short); // 540672
  const size_t AM_BYTES  = (size_t)BATCH * HID * sizeof(float);                 // 262144

  if (ws_size >= W1F_BYTES + AM_BYTES) {
    unsigned short* w1f = (unsigned short*)d_ws;
    float* am = (float*)((char*)d_ws + W1F_BYTES);
    k_prep<<<CONV_BLK + AM_BLK, 256, 0, stream>>>(w1, men, w1f, am);
    k_main<<<MAIN_BLK, 256, 0, stream>>>(all_m, men, pw, topi, rough, w1f, am,
                                         b1, wout, bout, out);
  } else {
    k_eps<<<1, BATCH, 0, stream>>>(out);
    k_fb<<<M_TOT, 128, 0, stream>>>(all_m, men, pw, topi, rough, w1, b1, wout, bout, out);
  }
}

// Round 7
// 54.846 us; speedup vs baseline: 2.5527x; 1.3829x over previous
//
#include <hip/hip_runtime.h>

#define N_MENT   10000
#define BATCH    512
#define N_ANTS   50
#define EMB      1024
#define PW_EMB   64
#define IN_F     3136       // 3*EMB + PW_EMB
#define HID      128
#define M_TOT    (BATCH * N_ANTS)   // 25600
#define EPS_VAL  1e-7f
#define SLOPE    0.01f

#define NKT      98         // IN_F/32 k-tiles, permuted: chunk c -> [a,a,b,b,s,s], then pw,pw
#define CONV_BLK 196        // 8 tn * 98 tk * 64 lanes / 256
#define MAIN_BLK (M_TOT / 32)   // 800

using f32x4 = __attribute__((ext_vector_type(4))) float;
using s16x8 = __attribute__((ext_vector_type(8))) short;
using u16x8 = __attribute__((ext_vector_type(8))) unsigned short;

__device__ __forceinline__ unsigned short f2bf(float f) {
  unsigned u = __builtin_bit_cast(unsigned, f);
  u += 0x7FFFu + ((u >> 16) & 1u);   // RNE
  return (unsigned short)(u >> 16);
}

// pack 8 f32 -> 8 bf16 (RNE) via v_cvt_pk_bf16_f32 (bit-equal to f2bf; verified R4-R6)
__device__ __forceinline__ u16x8 pack8(float4 lo, float4 hi) {
  union { u16x8 v; unsigned u[4]; } r;
  asm("v_cvt_pk_bf16_f32 %0, %1, %2" : "=v"(r.u[0]) : "v"(lo.x), "v"(lo.y));
  asm("v_cvt_pk_bf16_f32 %0, %1, %2" : "=v"(r.u[1]) : "v"(lo.z), "v"(lo.w));
  asm("v_cvt_pk_bf16_f32 %0, %1, %2" : "=v"(r.u[2]) : "v"(hi.x), "v"(hi.y));
  asm("v_cvt_pk_bf16_f32 %0, %1, %2" : "=v"(r.u[3]) : "v"(hi.z), "v"(hi.w));
  return r.v;
}

// permuted k-tile -> original W1 row base.
//   tk in [0,96): chunk c = tk/6, r = tk%6; region = r>>1 (0=a,1=b,2=sim), ks = r&1
//                 orig = region*1024 + c*64 + ks*32
//   tk 96,97   -> pw rows 3072 + (tk-96)*32
__device__ __forceinline__ int tile_orig_k(int tk) {
  if (tk >= 96) return 3072 + (tk - 96) * 32;
  const int c = tk / 6, r = tk % 6;
  return (r >> 1) * 1024 + c * 64 + (r & 1) * 32;
}

// ---- kernel 0: W1 [3136][128] f32 -> w1f in MFMA B-fragment-linear order ----
// w1f element index = ((tn*NKT + tk)*64 + lane)*8 + j
//   lane = ln + lg*16 holds B[col = tn*16+ln][k = orig_k(tk) + lg*8 + j]
__global__ __launch_bounds__(256) void k_convert(const float* __restrict__ w1,
                                                 unsigned short* __restrict__ w1f) {
  const int id   = blockIdx.x * 256 + threadIdx.x;   // 0..50175
  const int lane = id & 63;
  const int tile = id >> 6;                          // 0..783 = tn*98 + tk
  const int tk   = tile % NKT, tn = tile / NKT;
  const int n    = tn * 16 + (lane & 15);
  const int k    = tile_orig_k(tk) + (lane >> 4) * 8;
  u16x8 o;
  #pragma unroll
  for (int j = 0; j < 8; ++j) o[j] = f2bf(w1[(size_t)(k + j) * HID + n]);
  *(u16x8*)(w1f + (size_t)id * 8) = o;
}

// ---- kernel 1: full fused GEMM, K = 3136 (a | b | a*b | pw), BM=32 ----------
// Per chunk c: one set of a/b row loads feeds THREE LDS tiles (a, b, a*b);
// one barrier per chunk, 24 MFMA per wave per chunk. W-frags for the chunk
// are register-loaded BEFORE staging (independent of LDS; L2 latency hides
// under pack + barrier + early MFMAs).
__global__ __launch_bounds__(256) void k_main(
    const float* __restrict__ all_m, const float* __restrict__ men,
    const float* __restrict__ pw, const int* __restrict__ topi,
    const float* __restrict__ rough, const unsigned short* __restrict__ w1f,
    const float* __restrict__ b1, const float* __restrict__ wout,
    const float* __restrict__ bout, float* __restrict__ out) {
  __shared__ __align__(16) unsigned short Xs[2][3][32 * 72];
  __shared__ float red[4 * 32];

  const int t  = threadIdx.x;
  const int m0 = blockIdx.x * 32;

  const int sr = t >> 3, sq = t & 7;          // staging: row sr, 8-col group sq
  const int m  = m0 + sr;
  const int bb = m / N_ANTS;
  const int bidx = topi[m];
  const float* pA = men   + (size_t)bb   * EMB    + sq * 8;
  const float* pB = all_m + (size_t)bidx * EMB    + sq * 8;
  const float* pP = pw    + (size_t)m    * PW_EMB + sq * 8;

  const int lane = t & 63, wid = t >> 6;
  const int ln = lane & 15, lg = lane >> 4;
  const int wcol = wid * 32;
  // fragment base for n-tile (2*wid + nj), k-tile tk:
  //   w1f + ((2*wid+nj)*NKT + tk)*512 + lane*8
  const unsigned short* wfA = w1f + ((size_t)(2 * wid)     * NKT) * 512 + lane * 8;
  const unsigned short* wfB = w1f + ((size_t)(2 * wid + 1) * NKT) * 512 + lane * 8;

  f32x4 acc[2][2] = {};

  float4 a0 = ((const float4*)pA)[0], a1 = ((const float4*)pA)[1];
  float4 b0 = ((const float4*)pB)[0], b1v = ((const float4*)pB)[1];

  int buf = 0;
  for (int c = 0; c < 16; ++c) {
    // this chunk's 12 W-fragments first (VMEM issues before LDS work)
    s16x8 wr[12];
    #pragma unroll
    for (int j6 = 0; j6 < 6; ++j6) {
      wr[j6 * 2]     = *(const s16x8*)(wfA + (size_t)(c * 6 + j6) * 512);
      wr[j6 * 2 + 1] = *(const s16x8*)(wfB + (size_t)(c * 6 + j6) * 512);
    }

    // stage three tiles: 0 = a, 1 = b, 2 = a*b
    *(u16x8*)&Xs[buf][0][sr * 72 + sq * 8] = pack8(a0, a1);
    *(u16x8*)&Xs[buf][1][sr * 72 + sq * 8] = pack8(b0, b1v);
    float4 s0 = make_float4(a0.x * b0.x,  a0.y * b0.y,  a0.z * b0.z,  a0.w * b0.w);
    float4 s1 = make_float4(a1.x * b1v.x, a1.y * b1v.y, a1.z * b1v.z, a1.w * b1v.w);
    *(u16x8*)&Xs[buf][2][sr * 72 + sq * 8] = pack8(s0, s1);

    // prefetch next chunk's a/b rows (or pw at the end)
    if (c < 15) {
      const float* qA = pA + (c + 1) * 64;
      const float* qB = pB + (c + 1) * 64;
      a0 = ((const float4*)qA)[0]; a1 = ((const float4*)qA)[1];
      b0 = ((const float4*)qB)[0]; b1v = ((const float4*)qB)[1];
    } else {
      a0 = ((const float4*)pP)[0]; a1 = ((const float4*)pP)[1];
    }

    __syncthreads();
    #pragma unroll
    for (int j6 = 0; j6 < 6; ++j6) {
      const int reg = j6 >> 1, ks = j6 & 1;
      s16x8 x0 = *(const s16x8*)&Xs[buf][reg][ln * 72        + ks * 32 + lg * 8];
      s16x8 x1 = *(const s16x8*)&Xs[buf][reg][(16 + ln) * 72 + ks * 32 + lg * 8];
      acc[0][0] = __builtin_amdgcn_mfma_f32_16x16x32_bf16(x0, wr[j6 * 2],     acc[0][0], 0, 0, 0);
      acc[0][1] = __builtin_amdgcn_mfma_f32_16x16x32_bf16(x0, wr[j6 * 2 + 1], acc[0][1], 0, 0, 0);
      acc[1][0] = __builtin_amdgcn_mfma_f32_16x16x32_bf16(x1, wr[j6 * 2],     acc[1][0], 0, 0, 0);
      acc[1][1] = __builtin_amdgcn_mfma_f32_16x16x32_bf16(x1, wr[j6 * 2 + 1], acc[1][1], 0, 0, 0);
    }
    buf ^= 1;
  }

  // pw chunk: a0/a1 hold pw values; k-tiles 96,97
  {
    s16x8 wr[4];
    #pragma unroll
    for (int ks = 0; ks < 2; ++ks) {
      wr[ks * 2]     = *(const s16x8*)(wfA + (size_t)(96 + ks) * 512);
      wr[ks * 2 + 1] = *(const s16x8*)(wfB + (size_t)(96 + ks) * 512);
    }
    *(u16x8*)&Xs[buf][0][sr * 72 + sq * 8] = pack8(a0, a1);
    __syncthreads();
    #pragma unroll
    for (int ks = 0; ks < 2; ++ks) {
      s16x8 x0 = *(const s16x8*)&Xs[buf][0][ln * 72        + ks * 32 + lg * 8];
      s16x8 x1 = *(const s16x8*)&Xs[buf][0][(16 + ln) * 72 + ks * 32 + lg * 8];
      acc[0][0] = __builtin_amdgcn_mfma_f32_16x16x32_bf16(x0, wr[ks * 2],     acc[0][0], 0, 0, 0);
      acc[0][1] = __builtin_amdgcn_mfma_f32_16x16x32_bf16(x0, wr[ks * 2 + 1], acc[0][1], 0, 0, 0);
      acc[1][0] = __builtin_amdgcn_mfma_f32_16x16x32_bf16(x1, wr[ks * 2],     acc[1][0], 0, 0, 0);
      acc[1][1] = __builtin_amdgcn_mfma_f32_16x16x32_bf16(x1, wr[ks * 2 + 1], acc[1][1], 0, 0, 0);
    }
  }

  // epilogue: + b1, leaky, dot W_out, reduce over n, + rough, write
  const int n0 = wcol + ln, n1 = wcol + 16 + ln;
  const float bias0 = b1[n0], bias1 = b1[n1];
  const float w_0 = wout[n0], w_1 = wout[n1];
  #pragma unroll
  for (int mf = 0; mf < 2; ++mf)
    #pragma unroll
    for (int e = 0; e < 4; ++e) {
      const int ml = mf * 16 + lg * 4 + e;
      float h0 = acc[mf][0][e] + bias0;
      float h1 = acc[mf][1][e] + bias1;
      h0 = h0 > 0.f ? h0 : SLOPE * h0;
      h1 = h1 > 0.f ? h1 : SLOPE * h1;
      float ss = h0 * w_0 + h1 * w_1;
      ss += __shfl_xor(ss, 1);
      ss += __shfl_xor(ss, 2);
      ss += __shfl_xor(ss, 4);
      ss += __shfl_xor(ss, 8);
      if (ln == 0) red[wid * 32 + ml] = ss;
    }
  __syncthreads();
  if (t < 32) {
    const int gm = m0 + t;
    const int gb = gm / N_ANTS;
    const int ga = gm - gb * N_ANTS;
    out[(size_t)gb * (N_ANTS + 1) + 1 + ga] =
        rough[gm] + red[t] + red[32 + t] + red[64 + t] + red[96 + t] + bout[0];
  }
  if (t == 0) {   // EPSILON dummy column (duplicate same-value writes benign)
    for (int g = m0 / N_ANTS; g <= (m0 + 31) / N_ANTS; ++g)
      out[(size_t)g * (N_ANTS + 1)] = EPS_VAL;
  }
}

// ---- fallback (exact f32, used only if workspace too small) -----------------
__global__ void k_eps(float* __restrict__ out) {
  out[(size_t)threadIdx.x * (N_ANTS + 1)] = EPS_VAL;
}

__global__ __launch_bounds__(128) void k_fb(const float* __restrict__ all_m,
                                            const float* __restrict__ men,
                                            const float* __restrict__ pw,
                                            const int*   __restrict__ topi,
                                            const float* __restrict__ rough,
                                            const float* __restrict__ w1,
                                            const float* __restrict__ b1,
                                            const float* __restrict__ wout,
                                            const float* __restrict__ bout,
                                            float* __restrict__ out) {
  __shared__ float xs[IN_F];
  __shared__ float hred[HID];
  const int pair = blockIdx.x;
  const int t = threadIdx.x;
  const int bb = pair / N_ANTS;
  const int idx = topi[pair];
  const float* pA = men + (size_t)bb * EMB;
  const float* pB = all_m + (size_t)idx * EMB;
  for (int k = t; k < EMB; k += 128) {
    float a = pA[k], b = pB[k];
    xs[k] = a; xs[EMB + k] = b; xs[2 * EMB + k] = a * b;
  }
  if (t < PW_EMB) xs[3 * EMB + t] = pw[(size_t)pair * PW_EMB + t];
  __syncthreads();
  float acc = 0.f;
  for (int k = 0; k < IN_F; ++k) acc = fmaf(xs[k], w1[(size_t)k * HID + t], acc);
  acc += b1[t];
  acc = acc > 0.f ? acc : SLOPE * acc;
  hred[t] = acc * wout[t];
  __syncthreads();
  for (int off = 64; off > 0; off >>= 1) {
    if (t < off) hred[t] += hred[t + off];
    __syncthreads();
  }
  if (t == 0)
    out[(size_t)bb * (N_ANTS + 1) + 1 + (pair - bb * N_ANTS)] = rough[pair] + hred[0] + bout[0];
}

extern "C" void kernel_launch(void* const* d_in, const int* in_sizes, int n_in,
                              void* d_out, int out_size, void* d_ws, size_t ws_size,
                              hipStream_t stream) {
  const float* all_m = (const float*)d_in[0];
  const float* men   = (const float*)d_in[1];
  const float* pw    = (const float*)d_in[2];
  const int*   topi  = (const int*)  d_in[3];
  const float* rough = (const float*)d_in[4];
  const float* w1    = (const float*)d_in[5];
  const float* b1    = (const float*)d_in[6];
  const float* wout  = (const float*)d_in[7];
  const float* bout  = (const float*)d_in[8];
  float* out = (float*)d_out;

  const size_t W1F_BYTES = (size_t)HID * IN_F * sizeof(unsigned short);   // 802816

  if (ws_size >= W1F_BYTES) {
    unsigned short* w1f = (unsigned short*)d_ws;
    k_convert<<<CONV_BLK, 256, 0, stream>>>(w1, w1f);
    k_main<<<MAIN_BLK, 256, 0, stream>>>(all_m, men, pw, topi, rough, w1f,
                                         b1, wout, bout, out);
  } else {
    k_eps<<<1, BATCH, 0, stream>>>(out);
    k_fb<<<M_TOT, 128, 0, stream>>>(all_m, men, pw, topi, rough, w1, b1, wout, bout, out);
  }
}